// Round 3
// baseline (392.792 us; speedup 1.0000x reference)
//
#include <hip/hip_runtime.h>

typedef _Float16 f16x8 __attribute__((ext_vector_type(8)));
typedef float f32x4 __attribute__((ext_vector_type(4)));

#define CDIM 256
#define NE 1024
#define HW 4096        // H*W
#define CHW 1048576    // C*H*W
#define OUT_COS 262144 // 16*64*256
#define N_PIX 65536
#define NT 64          // 16-code tiles in codebook

// ws layout:
//   [0, 512K)        codebook hi halves, TILED: jt*4096 + f*512 + q*128 + n*8 + r
//                    (code = jt*16+n, dim = f*32+q*8+r)
//   [512K, 1M)       codebook lo halves, same tiling
//   [1M, 1M+4K)      0.5*||c||^2 (fp32, accumulated in fp64)

__global__ void prep_kernel(const float* __restrict__ cb,
                            _Float16* __restrict__ hi,
                            _Float16* __restrict__ lo,
                            float* __restrict__ cb2h) {
    int code = blockIdx.x;
    int lane = threadIdx.x; // 64 threads = 1 wave
    int jt = code >> 4, n = code & 15;
    const float* row = cb + code * CDIM;
    double s = 0.0;
    #pragma unroll
    for (int i = 0; i < 4; ++i) {
        int c = i * 64 + lane;
        float x = row[c];
        s += (double)x * (double)x;
        _Float16 h = (_Float16)x;
        float r = x - (float)h;
        int f = c >> 5, q = (c >> 3) & 3, rr = c & 7;
        size_t off = (size_t)jt * 4096 + f * 512 + q * 128 + n * 8 + rr;
        hi[off] = h;
        lo[off] = (_Float16)r;
    }
    #pragma unroll
    for (int off = 32; off > 0; off >>= 1)
        s += __shfl_down(s, off, 64);
    if (lane == 0) cb2h[code] = (float)(0.5 * s);
}

__device__ __forceinline__ void gl_lds16(const _Float16* g, _Float16* l) {
    // lds dest is wave-uniform base + lane*16; gptr is per-lane.
    __builtin_amdgcn_global_load_lds(
        (const __attribute__((address_space(1))) unsigned int*)g,
        (__attribute__((address_space(3))) unsigned int*)l, 16, 0, 0);
}

// Fused z+gt argmin. Grid 1024: blocks [0,512) -> z, [512,1024) -> gt.
// Block = 128 consecutive pixels; 4 waves x 32 rows (2 row-groups of 16).
// Full K=256 of A (hi+lo fp16) in registers: 128 VGPRs.
// B: 16-code tiles double-buffered in LDS via global_load_lds.
// 4 MFMA acc chains/wave (fits 170-VGPR cap for 3 waves/SIMD).
__launch_bounds__(256, 3)
__global__ void argmin_kernel(const float* __restrict__ Z,
                              const float* __restrict__ GT,
                              const _Float16* __restrict__ ghi,
                              const _Float16* __restrict__ glo,
                              const float* __restrict__ cb2h,
                              float* __restrict__ out_z,
                              float* __restrict__ out_gt) {
    __shared__ __align__(16) _Float16 lbuf[2][8192]; // [hi 4096 | lo 4096]
    const int wave = threadIdx.x >> 6;
    const int lane = threadIdx.x & 63;
    const int quad = lane >> 4;
    const int l15 = lane & 15;
    const int half = blockIdx.x >> 9;               // 0 = z, 1 = gt
    const float* X = half ? GT : Z;
    float* out_idx = half ? out_gt : out_z;
    const int p0 = (blockIdx.x & 511) * 128;

    // ---- A: rowgroup g holds pixels p0 + wave*32 + g*16 + l15, K=256 ----
    // A-frag layout (verified R1): A[m=l15][k=quad*8+j] per 32-dim frag f.
    f16x8 ahi[2][8], alo[2][8];
    #pragma unroll
    for (int g = 0; g < 2; ++g) {
        const int p = p0 + wave * 32 + g * 16 + l15;
        const float* xbase = X + (size_t)(p >> 12) * CHW + (p & 4095);
        #pragma unroll
        for (int f = 0; f < 8; ++f) {
            #pragma unroll
            for (int j = 0; j < 8; ++j) {
                int c = f * 32 + quad * 8 + j;
                float x = xbase[(size_t)c * HW];
                _Float16 h = (_Float16)x;
                ahi[g][f][j] = h;
                alo[g][f][j] = (_Float16)(x - (float)h);
            }
        }
    }

    float bestv[2][4];
    int   besti[2][4];
    #pragma unroll
    for (int g = 0; g < 2; ++g)
        #pragma unroll
        for (int r = 0; r < 4; ++r) { bestv[g][r] = 3.4e38f; besti[g][r] = 0; }

    // stage tile jt into buffer b: 16 KB = 16 x 1KB instrs, 4 per wave
    auto stage = [&](int b, int jt) {
        #pragma unroll
        for (int i = 0; i < 2; ++i) {
            const int off = wave * 1024 + i * 512;
            gl_lds16(ghi + (size_t)jt * 4096 + off + lane * 8, &lbuf[b][off]);
            gl_lds16(glo + (size_t)jt * 4096 + off + lane * 8, &lbuf[b][4096 + off]);
        }
    };

    stage(0, 0);
    __syncthreads();

    for (int jt = 0; jt < NT; ++jt) {
        const int cur = jt & 1;
        if (jt < NT - 1) stage(cur ^ 1, jt + 1);

        const float c2 = cb2h[jt * 16 + l15]; // this lane's code column

        // 4 chains: accP[g] takes hh then lh (4-instr dep spacing); accQ[g] takes hl.
        f32x4 accP[2], accQ[2];
        #pragma unroll
        for (int g = 0; g < 2; ++g) {
            accP[g] = (f32x4){0.f, 0.f, 0.f, 0.f};
            accQ[g] = (f32x4){0.f, 0.f, 0.f, 0.f};
        }

        #pragma unroll
        for (int f = 0; f < 8; ++f) {
            const int boff = f * 512 + quad * 128 + l15 * 8;
            f16x8 bh = *(const f16x8*)&lbuf[cur][boff];
            f16x8 bl = *(const f16x8*)&lbuf[cur][4096 + boff];
            accP[0] = __builtin_amdgcn_mfma_f32_16x16x32_f16(ahi[0][f], bh, accP[0], 0, 0, 0);
            accP[1] = __builtin_amdgcn_mfma_f32_16x16x32_f16(ahi[1][f], bh, accP[1], 0, 0, 0);
            accQ[0] = __builtin_amdgcn_mfma_f32_16x16x32_f16(ahi[0][f], bl, accQ[0], 0, 0, 0);
            accQ[1] = __builtin_amdgcn_mfma_f32_16x16x32_f16(ahi[1][f], bl, accQ[1], 0, 0, 0);
            accP[0] = __builtin_amdgcn_mfma_f32_16x16x32_f16(alo[0][f], bh, accP[0], 0, 0, 0);
            accP[1] = __builtin_amdgcn_mfma_f32_16x16x32_f16(alo[1][f], bh, accP[1], 0, 0, 0);
        }

        const int n = jt * 16 + l15;
        #pragma unroll
        for (int g = 0; g < 2; ++g) {
            #pragma unroll
            for (int r = 0; r < 4; ++r) {
                float s = c2 - (accP[g][r] + accQ[g][r]);
                if (s < bestv[g][r]) { bestv[g][r] = s; besti[g][r] = n; }
            }
        }
        __syncthreads(); // waves done reading cur; staging of nxt drained
    }

    // min over the 16 codes/lane-group; first-index tie-break.
    #pragma unroll
    for (int g = 0; g < 2; ++g) {
        #pragma unroll
        for (int r = 0; r < 4; ++r) {
            float bv = bestv[g][r];
            int   bi = besti[g][r];
            #pragma unroll
            for (int off = 8; off > 0; off >>= 1) {
                float ov = __shfl_xor(bv, off, 64);
                int   oi = __shfl_xor(bi, off, 64);
                if (ov < bv || (ov == bv && oi < bi)) { bv = ov; bi = oi; }
            }
            if (l15 == 0) {
                // C/D: reg r -> row quad*4+r (verified R1)
                out_idx[p0 + wave * 32 + g * 16 + quad * 4 + r] = (float)bi;
            }
        }
    }
}

// cosine over the H axis: one block per (b,w), one thread per channel c.
__global__ void cosine_kernel(const float* __restrict__ cb,
                              const float* __restrict__ idx_z_f,
                              const float* __restrict__ idx_gt_f,
                              float* __restrict__ out_cos) {
    const int bw = blockIdx.x;
    const int c = threadIdx.x;
    const int b = bw >> 6, w = bw & 63;
    float num = 0.f, sa = 0.f, sb = 0.f;
    for (int h = 0; h < 64; ++h) {
        const int p = b * 4096 + h * 64 + w;
        const int ig = (int)idx_gt_f[p];
        const int iq = (int)idx_z_f[p];
        const float av = cb[ig * CDIM + c];
        const float bv = cb[iq * CDIM + c];
        num += av * bv;
        sa += av * av;
        sb += bv * bv;
    }
    const float nx = fmaxf(sqrtf(sa), 1e-8f);
    const float ny = fmaxf(sqrtf(sb), 1e-8f);
    out_cos[bw * CDIM + c] = num / (nx * ny);
}

extern "C" void kernel_launch(void* const* d_in, const int* in_sizes, int n_in,
                              void* d_out, int out_size, void* d_ws, size_t ws_size,
                              hipStream_t stream) {
    const float* z  = (const float*)d_in[0];
    const float* gt = (const float*)d_in[1];
    const float* cb = (const float*)d_in[2];
    float* out = (float*)d_out;

    _Float16* hi = (_Float16*)d_ws;
    _Float16* lo = hi + NE * CDIM;
    float* cb2h = (float*)(lo + NE * CDIM);

    float* out_cos    = out;                   // (16,64,256)
    float* out_idx_gt = out + OUT_COS;         // (65536,1)
    float* out_idx_z  = out + OUT_COS + N_PIX; // (65536,1)

    prep_kernel<<<NE, 64, 0, stream>>>(cb, hi, lo, cb2h);
    argmin_kernel<<<1024, 256, 0, stream>>>(z, gt, hi, lo, cb2h, out_idx_z, out_idx_gt);
    cosine_kernel<<<1024, 256, 0, stream>>>(cb, out_idx_z, out_idx_gt, out_cos);
}

// Round 4
// 322.100 us; speedup vs baseline: 1.2195x; 1.2195x over previous
//
#include <hip/hip_runtime.h>

typedef _Float16 f16x8 __attribute__((ext_vector_type(8)));
typedef float f32x4 __attribute__((ext_vector_type(4)));

#define CDIM 256
#define NE 1024
#define HW 4096        // H*W
#define CHW 1048576    // C*H*W
#define OUT_COS 262144 // 16*64*256
#define N_PIX 65536
#define NT 64          // 16-code tiles in codebook

// ws layout:
//   [0, 512K)        codebook hi halves, TILED: jt*4096 + f*512 + q*128 + n*8 + r
//                    (code = jt*16+n, dim = f*32+q*8+r)
//   [512K, 1M)       codebook lo halves, same tiling
//   [1M, 1M+4K)      0.5*||c||^2 (fp32, accumulated in fp64)

__global__ void prep_kernel(const float* __restrict__ cb,
                            _Float16* __restrict__ hi,
                            _Float16* __restrict__ lo,
                            float* __restrict__ cb2h) {
    int code = blockIdx.x;
    int lane = threadIdx.x; // 64 threads = 1 wave
    int jt = code >> 4, n = code & 15;
    const float* row = cb + code * CDIM;
    double s = 0.0;
    #pragma unroll
    for (int i = 0; i < 4; ++i) {
        int c = i * 64 + lane;
        float x = row[c];
        s += (double)x * (double)x;
        _Float16 h = (_Float16)x;
        float r = x - (float)h;
        int f = c >> 5, q = (c >> 3) & 3, rr = c & 7;
        size_t off = (size_t)jt * 4096 + f * 512 + q * 128 + n * 8 + rr;
        hi[off] = h;
        lo[off] = (_Float16)r;
    }
    #pragma unroll
    for (int off = 32; off > 0; off >>= 1)
        s += __shfl_down(s, off, 64);
    if (lane == 0) cb2h[code] = (float)(0.5 * s);
}

__device__ __forceinline__ void gl_lds16(const _Float16* g, _Float16* l) {
    // lds dest is wave-uniform base + lane*16; gptr is per-lane.
    __builtin_amdgcn_global_load_lds(
        (const __attribute__((address_space(1))) unsigned int*)g,
        (__attribute__((address_space(3))) unsigned int*)l, 16, 0, 0);
}

// Fused z+gt argmin. Grid 1024: blocks [0,512) -> z, [512,1024) -> gt.
// Block = 128 consecutive pixels; 4 waves x 32 rows (2 row-groups of 16).
// Full K=256 of A (hi+lo fp16) in registers. B double-buffered in LDS.
// Tile-order STAGGER per block: co-resident blocks process different
// codebook tiles at any instant, so one block's ds_read burst overlaps the
// other's MFMA phase (barrier phase-lock breaker).
// __launch_bounds__(256,2): R2-proven register config (108 VGPR, no spill).
__launch_bounds__(256, 2)
__global__ void argmin_kernel(const float* __restrict__ Z,
                              const float* __restrict__ GT,
                              const _Float16* __restrict__ ghi,
                              const _Float16* __restrict__ glo,
                              const float* __restrict__ cb2h,
                              float* __restrict__ out_z,
                              float* __restrict__ out_gt) {
    __shared__ __align__(16) _Float16 lbuf[2][8192]; // [hi 4096 | lo 4096]
    const int wave = threadIdx.x >> 6;
    const int lane = threadIdx.x & 63;
    const int quad = lane >> 4;
    const int l15 = lane & 15;
    const int half = blockIdx.x >> 9;               // 0 = z, 1 = gt
    const float* X = half ? GT : Z;
    float* out_idx = half ? out_gt : out_z;
    const int p0 = (blockIdx.x & 511) * 128;
    const int tile_start = (blockIdx.x * 37) & 63;  // bijective stagger

    // ---- A: rowgroup g holds pixels p0 + wave*32 + g*16 + l15, K=256 ----
    // A-frag layout (verified R1): A[m=l15][k=quad*8+j] per 32-dim frag f.
    f16x8 ahi[2][8], alo[2][8];
    #pragma unroll
    for (int g = 0; g < 2; ++g) {
        const int p = p0 + wave * 32 + g * 16 + l15;
        const float* xbase = X + (size_t)(p >> 12) * CHW + (p & 4095);
        #pragma unroll
        for (int f = 0; f < 8; ++f) {
            #pragma unroll
            for (int j = 0; j < 8; ++j) {
                int c = f * 32 + quad * 8 + j;
                float x = xbase[(size_t)c * HW];
                _Float16 h = (_Float16)x;
                ahi[g][f][j] = h;
                alo[g][f][j] = (_Float16)(x - (float)h);
            }
        }
    }

    float bestv[2][4];
    int   besti[2][4];
    #pragma unroll
    for (int g = 0; g < 2; ++g)
        #pragma unroll
        for (int r = 0; r < 4; ++r) { bestv[g][r] = 3.4e38f; besti[g][r] = 0x7fffffff; }

    // stage physical tile pt into buffer b: 16 KB = 16 x 1KB instrs, 4/wave
    auto stage = [&](int b, int pt) {
        #pragma unroll
        for (int i = 0; i < 2; ++i) {
            const int off = wave * 1024 + i * 512;
            gl_lds16(ghi + (size_t)pt * 4096 + off + lane * 8, &lbuf[b][off]);
            gl_lds16(glo + (size_t)pt * 4096 + off + lane * 8, &lbuf[b][4096 + off]);
        }
    };

    stage(0, tile_start);
    __syncthreads();

    for (int jt = 0; jt < NT; ++jt) {
        const int cur = jt & 1;
        const int pt = (jt + tile_start) & 63;      // physical tile
        if (jt < NT - 1) stage(cur ^ 1, (pt + 1) & 63);

        const float c2 = cb2h[pt * 16 + l15]; // this lane's code column

        f32x4 accP[2], accQ[2];
        #pragma unroll
        for (int g = 0; g < 2; ++g) {
            accP[g] = (f32x4){0.f, 0.f, 0.f, 0.f};
            accQ[g] = (f32x4){0.f, 0.f, 0.f, 0.f};
        }

        #pragma unroll
        for (int f = 0; f < 8; ++f) {
            const int boff = f * 512 + quad * 128 + l15 * 8;
            f16x8 bh = *(const f16x8*)&lbuf[cur][boff];
            f16x8 bl = *(const f16x8*)&lbuf[cur][4096 + boff];
            accP[0] = __builtin_amdgcn_mfma_f32_16x16x32_f16(ahi[0][f], bh, accP[0], 0, 0, 0);
            accP[1] = __builtin_amdgcn_mfma_f32_16x16x32_f16(ahi[1][f], bh, accP[1], 0, 0, 0);
            accQ[0] = __builtin_amdgcn_mfma_f32_16x16x32_f16(ahi[0][f], bl, accQ[0], 0, 0, 0);
            accQ[1] = __builtin_amdgcn_mfma_f32_16x16x32_f16(ahi[1][f], bl, accQ[1], 0, 0, 0);
            accP[0] = __builtin_amdgcn_mfma_f32_16x16x32_f16(alo[0][f], bh, accP[0], 0, 0, 0);
            accP[1] = __builtin_amdgcn_mfma_f32_16x16x32_f16(alo[1][f], bh, accP[1], 0, 0, 0);
        }

        const int n = pt * 16 + l15;
        #pragma unroll
        for (int g = 0; g < 2; ++g) {
            #pragma unroll
            for (int r = 0; r < 4; ++r) {
                float s = c2 - (accP[g][r] + accQ[g][r]);
                // staggered scan: need explicit first-index tie-break
                if (s < bestv[g][r] ||
                    (s == bestv[g][r] && n < besti[g][r])) {
                    bestv[g][r] = s; besti[g][r] = n;
                }
            }
        }
        __syncthreads(); // waves done reading cur; staging of nxt drained
    }

    // min over the 16 codes/lane-group; first-index tie-break.
    #pragma unroll
    for (int g = 0; g < 2; ++g) {
        #pragma unroll
        for (int r = 0; r < 4; ++r) {
            float bv = bestv[g][r];
            int   bi = besti[g][r];
            #pragma unroll
            for (int off = 8; off > 0; off >>= 1) {
                float ov = __shfl_xor(bv, off, 64);
                int   oi = __shfl_xor(bi, off, 64);
                if (ov < bv || (ov == bv && oi < bi)) { bv = ov; bi = oi; }
            }
            if (l15 == 0) {
                // C/D: reg r -> row quad*4+r (verified R1)
                out_idx[p0 + wave * 32 + g * 16 + quad * 4 + r] = (float)bi;
            }
        }
    }
}

// cosine over the H axis: one block per (b,w), one thread per channel c.
// idx pairs staged to LDS once (scalar broadcast reads), h-loop unrolled x4
// for memory-level parallelism on the codebook gathers.
__global__ void cosine_kernel(const float* __restrict__ cb,
                              const float* __restrict__ idx_z_f,
                              const float* __restrict__ idx_gt_f,
                              float* __restrict__ out_cos) {
    __shared__ int s_ig[64], s_iq[64];
    const int bw = blockIdx.x;
    const int c = threadIdx.x;
    const int b = bw >> 6, w = bw & 63;
    if (c < 64) {
        s_ig[c] = (int)idx_gt_f[b * 4096 + c * 64 + w];
    } else if (c < 128) {
        int h = c - 64;
        s_iq[h] = (int)idx_z_f[b * 4096 + h * 64 + w];
    }
    __syncthreads();
    float num = 0.f, sa = 0.f, sb = 0.f;
    #pragma unroll 1
    for (int h = 0; h < 64; h += 4) {
        float av[4], bv[4];
        #pragma unroll
        for (int u = 0; u < 4; ++u) {
            av[u] = cb[s_ig[h + u] * CDIM + c];
            bv[u] = cb[s_iq[h + u] * CDIM + c];
        }
        #pragma unroll
        for (int u = 0; u < 4; ++u) {
            num += av[u] * bv[u];
            sa += av[u] * av[u];
            sb += bv[u] * bv[u];
        }
    }
    const float nx = fmaxf(sqrtf(sa), 1e-8f);
    const float ny = fmaxf(sqrtf(sb), 1e-8f);
    out_cos[bw * CDIM + c] = num / (nx * ny);
}

extern "C" void kernel_launch(void* const* d_in, const int* in_sizes, int n_in,
                              void* d_out, int out_size, void* d_ws, size_t ws_size,
                              hipStream_t stream) {
    const float* z  = (const float*)d_in[0];
    const float* gt = (const float*)d_in[1];
    const float* cb = (const float*)d_in[2];
    float* out = (float*)d_out;

    _Float16* hi = (_Float16*)d_ws;
    _Float16* lo = hi + NE * CDIM;
    float* cb2h = (float*)(lo + NE * CDIM);

    float* out_cos    = out;                   // (16,64,256)
    float* out_idx_gt = out + OUT_COS;         // (65536,1)
    float* out_idx_z  = out + OUT_COS + N_PIX; // (65536,1)

    prep_kernel<<<NE, 64, 0, stream>>>(cb, hi, lo, cb2h);
    argmin_kernel<<<1024, 256, 0, stream>>>(z, gt, hi, lo, cb2h, out_idx_z, out_idx_gt);
    cosine_kernel<<<1024, 256, 0, stream>>>(cb, out_idx_z, out_idx_gt, out_cos);
}

// Round 5
// 321.387 us; speedup vs baseline: 1.2222x; 1.0022x over previous
//
#include <hip/hip_runtime.h>

typedef _Float16 f16x8 __attribute__((ext_vector_type(8)));
typedef float f32x16 __attribute__((ext_vector_type(16)));

#define CDIM 256
#define NE 1024
#define HW 4096        // H*W
#define CHW 1048576    // C*H*W
#define OUT_COS 262144 // 16*64*256
#define N_PIX 65536
#define NT 32          // 32-code tiles in codebook

// ws layout (halves):
//   [0, 512K)   codebook hi, TILED: t*8192 + f*512 + q*256 + n*8 + r
//               code = t*32+n, dim = f*16 + q*8 + r   (f<16, q<2, r<8)
//   [512K, 1M)  codebook lo, same tiling
//   [1M, +4K)   0.5*||c||^2 fp32 (accumulated in fp64)

__global__ void prep_kernel(const float* __restrict__ cb,
                            _Float16* __restrict__ hi,
                            _Float16* __restrict__ lo,
                            float* __restrict__ cb2h) {
    int code = blockIdx.x;
    int lane = threadIdx.x; // 64 threads = 1 wave
    int t = code >> 5, n = code & 31;
    const float* row = cb + code * CDIM;
    double s = 0.0;
    #pragma unroll
    for (int i = 0; i < 4; ++i) {
        int d = i * 64 + lane;
        float x = row[d];
        s += (double)x * (double)x;
        _Float16 h = (_Float16)x;
        float rres = x - (float)h;
        int f = d >> 4, q = (d >> 3) & 1, rr = d & 7;
        size_t off = (size_t)t * 8192 + f * 512 + q * 256 + n * 8 + rr;
        hi[off] = h;
        lo[off] = (_Float16)rres;
    }
    #pragma unroll
    for (int off = 32; off > 0; off >>= 1)
        s += __shfl_down(s, off, 64);
    if (lane == 0) cb2h[code] = (float)(0.5 * s);
}

__device__ __forceinline__ void gl_lds16(const _Float16* g, _Float16* l) {
    // lds dest is wave-uniform base + lane*16; gptr is per-lane.
    __builtin_amdgcn_global_load_lds(
        (const __attribute__((address_space(1))) unsigned int*)g,
        (__attribute__((address_space(3))) unsigned int*)l, 16, 0, 0);
}

// Fused z+gt argmin. Grid 1024: blocks [0,512) -> z, [512,1024) -> gt.
// Block = 128 pixels; 4 waves x 32 pixels, 32x32x16 MFMA (2495 TF rate).
// A (negated hi/lo fp16, K=256) in registers: 128 VGPRs. B: 32-code tiles
// double-buffered in LDS (2x32KB). accP initialized to 0.5||c||^2 so MFMA
// accumulates c2 - dot directly (A negated) - no per-tile subtract.
__launch_bounds__(256, 2)
__global__ void argmin_kernel(const float* __restrict__ Z,
                              const float* __restrict__ GT,
                              const _Float16* __restrict__ ghi,
                              const _Float16* __restrict__ glo,
                              const float* __restrict__ cb2h,
                              float* __restrict__ out_z,
                              float* __restrict__ out_gt) {
    __shared__ __align__(16) _Float16 lbuf[2][16384]; // [hi 8192 | lo 8192]
    const int wave = threadIdx.x >> 6;
    const int lane = threadIdx.x & 63;
    const int l31 = lane & 31;
    const int qh = lane >> 5; // 0/1
    const int half = blockIdx.x >> 9;               // 0 = z, 1 = gt
    const float* X = half ? GT : Z;
    float* out_idx = half ? out_gt : out_z;
    const int p0 = (blockIdx.x & 511) * 128;

    // ---- A: wave owns pixels p0 + wave*32 + l31 (m = l31), K=256 ----
    // 32x32x16 A layout: A[m=lane&31][k = (lane>>5)*8 + j] per 16-dim frag f.
    // Stored NEGATED so MFMA accumulates -dot.
    const int p = p0 + wave * 32 + l31;
    const float* xbase = X + (size_t)(p >> 12) * CHW + (p & 4095);
    f16x8 nah[16], nal[16];
    #pragma unroll
    for (int f = 0; f < 16; ++f) {
        #pragma unroll
        for (int j = 0; j < 8; ++j) {
            int d = f * 16 + qh * 8 + j;
            float x = xbase[(size_t)d * HW];
            _Float16 h = (_Float16)x;
            _Float16 l = (_Float16)(x - (float)h);
            nah[f][j] = -h;
            nal[f][j] = -l;
        }
    }

    float bestv[16];
    float besti[16];
    #pragma unroll
    for (int r = 0; r < 16; ++r) { bestv[r] = 3.4e38f; besti[r] = 0.f; }

    // stage tile t into buffer b: 32 KB = 32 x 1KB instrs, 8 per wave.
    // LDS dest lane-offset (lane*16B) == source tiling (q*256+n*8 halves)
    // so stage and ds_read use identical per-lane addressing.
    auto stage = [&](int b, int t) {
        #pragma unroll
        for (int i = 0; i < 4; ++i) {
            const int f = wave * 4 + i;
            gl_lds16(ghi + (size_t)t * 8192 + f * 512 + lane * 8, &lbuf[b][f * 512]);
            gl_lds16(glo + (size_t)t * 8192 + f * 512 + lane * 8, &lbuf[b][8192 + f * 512]);
        }
    };

    stage(0, 0);
    __syncthreads();

    for (int t = 0; t < NT; ++t) {
        const int cur = t & 1;
        if (t < NT - 1) stage(cur ^ 1, t + 1);

        const float c2 = cb2h[t * 32 + l31]; // this lane's code column

        f32x16 accP, accQ;
        #pragma unroll
        for (int r = 0; r < 16; ++r) { accP[r] = c2; accQ[r] = 0.f; }

        #pragma unroll
        for (int f = 0; f < 16; ++f) {
            // B[k][n=l31]: contiguous 16B/lane, conflict-free
            f16x8 bh = *(const f16x8*)&lbuf[cur][f * 512 + lane * 8];
            f16x8 bl = *(const f16x8*)&lbuf[cur][8192 + f * 512 + lane * 8];
            accP = __builtin_amdgcn_mfma_f32_32x32x16_f16(nah[f], bh, accP, 0, 0, 0);
            accQ = __builtin_amdgcn_mfma_f32_32x32x16_f16(nah[f], bl, accQ, 0, 0, 0);
            accP = __builtin_amdgcn_mfma_f32_32x32x16_f16(nal[f], bh, accP, 0, 0, 0);
        }

        const float nf = (float)(t * 32 + l31);
        #pragma unroll
        for (int r = 0; r < 16; ++r) {
            float s = accP[r] + accQ[r]; // = c2 - dot
            // ascending scan + strict < keeps first index (numpy argmin)
            if (s < bestv[r]) { bestv[r] = s; besti[r] = nf; }
        }
        __syncthreads(); // waves done reading cur; staging of nxt drained
    }

    // min over the 32 lanes of each half-wave (same qh group holds the same
    // 16 rows); xor offsets 1..16 stay within the 32-lane group.
    #pragma unroll
    for (int r = 0; r < 16; ++r) {
        float bv = bestv[r];
        float bi = besti[r];
        #pragma unroll
        for (int off = 16; off > 0; off >>= 1) {
            float ov = __shfl_xor(bv, off, 64);
            float oi = __shfl_xor(bi, off, 64);
            if (ov < bv || (ov == bv && oi < bi)) { bv = ov; bi = oi; }
        }
        if (l31 == 0) {
            // 32x32 C/D: col=lane&31 (code), row=(r&3)+8*(r>>2)+4*qh (pixel)
            const int row = (r & 3) + 8 * (r >> 2) + 4 * qh;
            out_idx[p0 + wave * 32 + row] = bi;
        }
    }
}

// cosine over the H axis: one block per (b,w), one thread per channel c.
__global__ void cosine_kernel(const float* __restrict__ cb,
                              const float* __restrict__ idx_z_f,
                              const float* __restrict__ idx_gt_f,
                              float* __restrict__ out_cos) {
    __shared__ int s_ig[64], s_iq[64];
    const int bw = blockIdx.x;
    const int c = threadIdx.x;
    const int b = bw >> 6, w = bw & 63;
    if (c < 64) {
        s_ig[c] = (int)idx_gt_f[b * 4096 + c * 64 + w];
    } else if (c < 128) {
        int h = c - 64;
        s_iq[h] = (int)idx_z_f[b * 4096 + h * 64 + w];
    }
    __syncthreads();
    float num = 0.f, sa = 0.f, sb = 0.f;
    #pragma unroll 1
    for (int h = 0; h < 64; h += 4) {
        float av[4], bv[4];
        #pragma unroll
        for (int u = 0; u < 4; ++u) {
            av[u] = cb[s_ig[h + u] * CDIM + c];
            bv[u] = cb[s_iq[h + u] * CDIM + c];
        }
        #pragma unroll
        for (int u = 0; u < 4; ++u) {
            num += av[u] * bv[u];
            sa += av[u] * av[u];
            sb += bv[u] * bv[u];
        }
    }
    const float nx = fmaxf(sqrtf(sa), 1e-8f);
    const float ny = fmaxf(sqrtf(sb), 1e-8f);
    out_cos[bw * CDIM + c] = num / (nx * ny);
}

extern "C" void kernel_launch(void* const* d_in, const int* in_sizes, int n_in,
                              void* d_out, int out_size, void* d_ws, size_t ws_size,
                              hipStream_t stream) {
    const float* z  = (const float*)d_in[0];
    const float* gt = (const float*)d_in[1];
    const float* cb = (const float*)d_in[2];
    float* out = (float*)d_out;

    _Float16* hi = (_Float16*)d_ws;
    _Float16* lo = hi + NE * CDIM;
    float* cb2h = (float*)(lo + NE * CDIM);

    float* out_cos    = out;                   // (16,64,256)
    float* out_idx_gt = out + OUT_COS;         // (65536,1)
    float* out_idx_z  = out + OUT_COS + N_PIX; // (65536,1)

    prep_kernel<<<NE, 64, 0, stream>>>(cb, hi, lo, cb2h);
    argmin_kernel<<<1024, 256, 0, stream>>>(z, gt, hi, lo, cb2h, out_idx_z, out_idx_gt);
    cosine_kernel<<<1024, 256, 0, stream>>>(cb, out_idx_z, out_idx_gt, out_cos);
}